// Round 1
// baseline (18669.102 us; speedup 1.0000x reference)
//
#include <hip/hip_runtime.h>
#include <hip/hip_cooperative_groups.h>

namespace cg = cooperative_groups;

// Problem constants
constexpr int V = 4000, E = 512, H = 512, NB = 32, To = 128, Ti = 512;
constexpr int T_STEPS = 129;          // To + 1
constexpr int G4 = 2048;              // 4*H

// ws layout (float offsets)
constexpr size_t OFF_XPRE = 0;                               // [129][32][2048]
constexpr size_t OFF_WP0  = OFF_XPRE + (size_t)129*32*2048;  // [256][1024][8]
constexpr size_t OFF_WP1  = OFF_WP0 + (size_t)256*1024*8;
constexpr size_t OFF_H0   = OFF_WP1 + (size_t)256*1024*8;    // [2][512][32]
constexpr size_t OFF_C0   = OFF_H0 + 2*512*32;               // [512][32]
constexpr size_t OFF_C1   = OFF_C0 + 512*32;
constexpr size_t OFF_H1A  = OFF_C1 + 512*32;                 // [130][512][32]
constexpr size_t OFF_ATTC = OFF_H1A + (size_t)130*512*32;    // [130][512][32]
constexpr size_t OFF_HID  = OFF_ATTC + (size_t)130*512*32;   // [4128][512]
constexpr size_t OFF_PM   = OFF_HID + (size_t)4128*512;      // [256]
constexpr size_t OFF_PS   = OFF_PM + 256;                    // [256]
constexpr size_t OFF_PCTX = OFF_PS + 256;                    // [256][512]
constexpr size_t OFF_CPM  = OFF_PCTX + (size_t)256*512;      // [4128][16]
constexpr size_t OFF_CPS  = OFF_CPM + (size_t)4128*16;
constexpr size_t OFF_TGT  = OFF_CPS + (size_t)4128*16;       // [4128]

__device__ __forceinline__ float sigmf(float x) { return 1.0f / (1.0f + __expf(-x)); }

// ---------------- init: zero state buffers ----------------
__global__ __launch_bounds__(256) void k_init(float* ws) {
    int id = blockIdx.x * 256 + threadIdx.x;   // 0..81919
    int reg = id / 16384, off = id % 16384;
    size_t base;
    switch (reg) {
        case 0: base = OFF_H0; break;          // h0 ping buf 0
        case 1: base = OFF_C0; break;
        case 2: base = OFF_C1; break;
        case 3: base = OFF_H1A; break;         // h1_all slab 0
        default: base = OFF_ATTC; break;       // attc_all slab 0
    }
    ws[base + off] = 0.0f;
}

// ---------------- weight pre-pack for the recurrent skinny GEMMs ----------------
// Wp[b][k][r], b=0..255 owns 8 g-rows: gRow = (r>>1)*512 + b*2 + (r&1)
// LSTM0 combined K: k<512 -> W_ih0[gRow][512+k] (att part), k>=512 -> W_hh0[gRow][k-512]
__global__ __launch_bounds__(256) void k_pack0(const float* __restrict__ W_ih0,
                                               const float* __restrict__ W_hh0,
                                               float* __restrict__ Wp) {
    int p = blockIdx.x * 256 + threadIdx.x;    // 0..2097151
    int r = p & 7, k = (p >> 3) & 1023, b = p >> 13;
    int gRow = ((r >> 1) & 3) * 512 + b * 2 + (r & 1);
    float v = (k < 512) ? W_ih0[(size_t)gRow * 1024 + 512 + k]
                        : W_hh0[(size_t)gRow * 512 + (k - 512)];
    Wp[p] = v;
}
// LSTM1 combined K: k<512 -> W_ih1[gRow][k] (input=h0), k>=512 -> W_hh1[gRow][k-512]
__global__ __launch_bounds__(256) void k_pack1(const float* __restrict__ W_ih1,
                                               const float* __restrict__ W_hh1,
                                               float* __restrict__ Wp) {
    int p = blockIdx.x * 256 + threadIdx.x;
    int r = p & 7, k = (p >> 3) & 1023, b = p >> 13;
    int gRow = ((r >> 1) & 3) * 512 + b * 2 + (r & 1);
    float v = (k < 512) ? W_ih1[(size_t)gRow * 512 + k]
                        : W_hh1[(size_t)gRow * 512 + (k - 512)];
    Wp[p] = v;
}

// ---------------- X_pre GEMM: [4128][2048] = emb_rows @ W_ih0[:, :512].T + biases ----------------
__global__ __launch_bounds__(256) void k_xpre(const int* __restrict__ padded,
                                              const float* __restrict__ embedding,
                                              const float* __restrict__ W_ih0,
                                              const float* __restrict__ b_ih0,
                                              const float* __restrict__ b_hh0,
                                              float* __restrict__ Xpre) {
    __shared__ __align__(16) float At[32 * 33];
    __shared__ __align__(16) float Bt[32 * 68];
    __shared__ int toks[32];
    const int t = blockIdx.x, j0 = blockIdx.y * 64, tid = threadIdx.x;
    if (tid < 32) toks[tid] = (t == 0) ? 1 : padded[tid * 128 + (t - 1)];
    __syncthreads();
    const int ty = tid >> 4, tx = tid & 15;
    float acc[8];
#pragma unroll
    for (int i = 0; i < 8; ++i) acc[i] = 0.0f;
    for (int k0 = 0; k0 < 512; k0 += 32) {
        __syncthreads();
        {
            int r = tid >> 3, kk4 = tid & 7;
            float4 v = *(const float4*)(embedding + (size_t)toks[r] * 512 + k0 + kk4 * 4);
            At[(kk4 * 4 + 0) * 33 + r] = v.x;
            At[(kk4 * 4 + 1) * 33 + r] = v.y;
            At[(kk4 * 4 + 2) * 33 + r] = v.z;
            At[(kk4 * 4 + 3) * 33 + r] = v.w;
#pragma unroll
            for (int i2 = 0; i2 < 2; ++i2) {
                int f = tid + 256 * i2;
                int j = f >> 3, kb = f & 7;
                float4 w = *(const float4*)(W_ih0 + (size_t)(j0 + j) * 1024 + k0 + kb * 4);
                Bt[(kb * 4 + 0) * 68 + j] = w.x;
                Bt[(kb * 4 + 1) * 68 + j] = w.y;
                Bt[(kb * 4 + 2) * 68 + j] = w.z;
                Bt[(kb * 4 + 3) * 68 + j] = w.w;
            }
        }
        __syncthreads();
#pragma unroll
        for (int kk = 0; kk < 32; ++kk) {
            float a0 = At[kk * 33 + ty], a1 = At[kk * 33 + ty + 16];
            float4 b4 = *(const float4*)&Bt[kk * 68 + tx * 4];
            acc[0] += a0 * b4.x; acc[1] += a0 * b4.y; acc[2] += a0 * b4.z; acc[3] += a0 * b4.w;
            acc[4] += a1 * b4.x; acc[5] += a1 * b4.y; acc[6] += a1 * b4.z; acc[7] += a1 * b4.w;
        }
    }
    int j = j0 + tx * 4;
    float4 bi = *(const float4*)(b_ih0 + j);
    float4 bh = *(const float4*)(b_hh0 + j);
    int r0 = t * 32;
    float4 o0 = {acc[0] + bi.x + bh.x, acc[1] + bi.y + bh.y, acc[2] + bi.z + bh.z, acc[3] + bi.w + bh.w};
    float4 o1 = {acc[4] + bi.x + bh.x, acc[5] + bi.y + bh.y, acc[6] + bi.z + bh.z, acc[7] + bi.w + bh.w};
    *(float4*)(Xpre + (size_t)(r0 + ty) * 2048 + j) = o0;
    *(float4*)(Xpre + (size_t)(r0 + ty + 16) * 2048 + j) = o1;
}

// ---------------- LSTM phase (device func, used for both cells) ----------------
// Block b owns 8 g-rows (4 gates x 2 h-cols).  Thread (q=tid>>5, kq=tid&31):
// outer-product 8 rows x 4 samples, K interleaved by 32.
__device__ __forceinline__ void lstm_phase(
    const float* __restrict__ Wp,        // [b][1024][8] pack
    const float* __restrict__ srcA,      // K 0..511 source, [k][32]
    const float* __restrict__ srcB,      // K 512..1023 source, [k][32]
    const float* __restrict__ xpre_row,  // Xpre + t*32*2048, or nullptr
    const float* __restrict__ bia, const float* __restrict__ bib,  // biases if xpre null
    float* __restrict__ cT,              // [512][32] cell state (in-place)
    float* __restrict__ hOut,            // [512][32] new h
    int b, int tid, int q, int kq, float* sm) {
    float acc[8][4];
#pragma unroll
    for (int r = 0; r < 8; ++r)
#pragma unroll
        for (int s = 0; s < 4; ++s) acc[r][s] = 0.0f;

    for (int tile = 0; tile < 4; ++tile) {
        const int kt0 = tile * 256;
        const float* src = (tile < 2) ? (srcA + kt0 * 32) : (srcB + (kt0 - 512) * 32);
        __syncthreads();
        // stage xt[256][33]
#pragma unroll
        for (int jj = 0; jj < 8; ++jj) {
            int f = tid + jj * 256;         // float4 index 0..2047
            int lk = f >> 3, n4 = f & 7;
            float4 v = ((const float4*)src)[f];
            float* d = sm + lk * 33 + n4 * 4;
            d[0] = v.x; d[1] = v.y; d[2] = v.z; d[3] = v.w;
        }
        __syncthreads();
        const float* wrow = Wp + ((size_t)b * 1024 + kt0) * 8;
#pragma unroll
        for (int i = 0; i < 8; ++i) {
            int lk = kq + 32 * i;
            float4 wA = *(const float4*)(wrow + (size_t)lk * 8);
            float4 wB = *(const float4*)(wrow + (size_t)lk * 8 + 4);
            const float* xr = sm + lk * 33 + (q << 2);
            float x0 = xr[0], x1 = xr[1], x2 = xr[2], x3 = xr[3];
            acc[0][0] += wA.x * x0; acc[0][1] += wA.x * x1; acc[0][2] += wA.x * x2; acc[0][3] += wA.x * x3;
            acc[1][0] += wA.y * x0; acc[1][1] += wA.y * x1; acc[1][2] += wA.y * x2; acc[1][3] += wA.y * x3;
            acc[2][0] += wA.z * x0; acc[2][1] += wA.z * x1; acc[2][2] += wA.z * x2; acc[2][3] += wA.z * x3;
            acc[3][0] += wA.w * x0; acc[3][1] += wA.w * x1; acc[3][2] += wA.w * x2; acc[3][3] += wA.w * x3;
            acc[4][0] += wB.x * x0; acc[4][1] += wB.x * x1; acc[4][2] += wB.x * x2; acc[4][3] += wB.x * x3;
            acc[5][0] += wB.y * x0; acc[5][1] += wB.y * x1; acc[5][2] += wB.y * x2; acc[5][3] += wB.y * x3;
            acc[6][0] += wB.z * x0; acc[6][1] += wB.z * x1; acc[6][2] += wB.z * x2; acc[6][3] += wB.z * x3;
            acc[7][0] += wB.w * x0; acc[7][1] += wB.w * x1; acc[7][2] += wB.w * x2; acc[7][3] += wB.w * x3;
        }
    }
    // cross-kq reduction through LDS: red[kq][n*9+r], row stride 292
    __syncthreads();
#pragma unroll
    for (int r = 0; r < 8; ++r)
#pragma unroll
        for (int s = 0; s < 4; ++s) {
            int n = q * 4 + s;
            sm[kq * 292 + n * 9 + r] = acc[r][s];
        }
    __syncthreads();
    {
        int rr = tid >> 5, n = tid & 31;
        float g = 0.0f;
#pragma unroll
        for (int k2 = 0; k2 < 32; ++k2) g += sm[k2 * 292 + n * 9 + rr];
        sm[9344 + rr * 33 + n] = g;   // gv region, disjoint from red
    }
    __syncthreads();
    if (tid < 64) {
        int jl = tid >> 5, nn = tid & 31;
        float gi = sm[9344 + (0 + jl) * 33 + nn];
        float gf = sm[9344 + (2 + jl) * 33 + nn];
        float gg = sm[9344 + (4 + jl) * 33 + nn];
        float go = sm[9344 + (6 + jl) * 33 + nn];
        int j = b * 2 + jl;
        if (xpre_row) {
            const float* xp = xpre_row + (size_t)nn * 2048;
            gi += xp[j]; gf += xp[512 + j]; gg += xp[1024 + j]; go += xp[1536 + j];
        } else {
            gi += bia[j] + bib[j];
            gf += bia[512 + j] + bib[512 + j];
            gg += bia[1024 + j] + bib[1024 + j];
            go += bia[1536 + j] + bib[1536 + j];
        }
        float c = cT[j * 32 + nn];
        float cn = sigmf(gf) * c + sigmf(gi) * tanhf(gg);
        float hn = sigmf(go) * tanhf(cn);
        cT[j * 32 + nn] = cn;
        hOut[j * 32 + nn] = hn;
    }
}

// ---------------- cooperative sequential kernel ----------------
__global__ __launch_bounds__(256) void k_seq(float* ws, const int* __restrict__ padded,
                                             const float* __restrict__ enc,
                                             const float* __restrict__ b_ih1,
                                             const float* __restrict__ b_hh1) {
    cg::grid_group grid = cg::this_grid();
    __shared__ __align__(16) float sm[9728];
    const int b = blockIdx.x, tid = threadIdx.x;
    const int q = tid >> 5, kq = tid & 31;

    float* Xpre = ws + OFF_XPRE;
    float* h0   = ws + OFF_H0;
    float* c0   = ws + OFF_C0;
    float* c1   = ws + OFF_C1;
    float* h1a  = ws + OFF_H1A;
    float* attc = ws + OFF_ATTC;
    float* pm   = ws + OFF_PM;
    float* ps   = ws + OFF_PS;
    float* pctx = ws + OFF_PCTX;
    const float* Wp0 = ws + OFF_WP0;
    const float* Wp1 = ws + OFF_WP1;

    for (int t = 0; t < T_STEPS; ++t) {
        const int rd0 = t & 1, wr0 = rd0 ^ 1;
        // ---- P1: LSTM0 : x = [attc(t), h0(t-1)] ----
        lstm_phase(Wp0, attc + (size_t)t * 16384, h0 + (size_t)rd0 * 16384,
                   Xpre + (size_t)t * 32 * 2048, nullptr, nullptr,
                   c0, h0 + (size_t)wr0 * 16384, b, tid, q, kq, sm);
        grid.sync();
        // ---- P2: LSTM1 : x = [h0(t), h1(t-1)] ----
        lstm_phase(Wp1, h0 + (size_t)wr0 * 16384, h1a + (size_t)t * 16384,
                   nullptr, b_ih1, b_hh1,
                   c1, h1a + (size_t)(t + 1) * 16384, b, tid, q, kq, sm);
        grid.sync();
        // ---- P3a: attention partial (8 blocks per sample, 64 frames each) ----
        {
            const int n = b >> 3, ts0 = (b & 7) * 64;
            float* h_l = sm;          // 512
            float* scp = sm + 512;    // 256
            float* p_l = sm + 768;    // 64
            const float* h1t = h1a + (size_t)(t + 1) * 16384;
            {
                int k0 = tid * 2;
                h_l[k0]     = h1t[(size_t)k0 * 32 + n];
                h_l[k0 + 1] = h1t[(size_t)(k0 + 1) * 32 + n];
            }
            __syncthreads();
            {
                int ti = tid >> 2, kp = tid & 3;
                const float* er = enc + ((size_t)n * 512 + ts0 + ti) * 512 + kp * 128;
                const float* hr = h_l + kp * 128;
                float s = 0.0f;
#pragma unroll 8
                for (int k = 0; k < 128; k += 4) {
                    float4 e = *(const float4*)(er + k);
                    float4 hv = *(const float4*)(hr + k);
                    s += e.x * hv.x + e.y * hv.y + e.z * hv.z + e.w * hv.w;
                }
                scp[kp * 64 + ti] = s;
            }
            __syncthreads();
            if (tid < 64) {
                float sc = scp[tid] + scp[64 + tid] + scp[128 + tid] + scp[192 + tid];
                float m = sc;
                for (int o = 32; o; o >>= 1) m = fmaxf(m, __shfl_xor(m, o));
                float e = __expf(sc - m);
                float z = e;
                for (int o = 32; o; o >>= 1) z += __shfl_xor(z, o);
                p_l[tid] = e;
                if (tid == 0) { pm[b] = m; ps[b] = z; }
            }
            __syncthreads();
            {
                int k = tid * 2;
                float cv0 = 0.0f, cv1 = 0.0f;
                const float* eb = enc + ((size_t)n * 512 + ts0) * 512 + k;
#pragma unroll 4
                for (int ti = 0; ti < 64; ++ti) {
                    float w = p_l[ti];
                    float2 e = *(const float2*)(eb + (size_t)ti * 512);
                    cv0 += w * e.x; cv1 += w * e.y;
                }
                float2 o2 = {cv0, cv1};
                *(float2*)&pctx[(size_t)b * 512 + k] = o2;
            }
        }
        grid.sync();
        // ---- P3b: combine softmax partials -> attc(t+1) ----
        if (b < 64) {
            int n = b >> 1, kh = (b & 1) * 256;
            int k = kh + tid;
            float M = -1e30f;
#pragma unroll
            for (int c = 0; c < 8; ++c) M = fmaxf(M, pm[n * 8 + c]);
            float Z = 0.0f, ctxv = 0.0f;
#pragma unroll
            for (int c = 0; c < 8; ++c) {
                float scl = __expf(pm[n * 8 + c] - M);
                Z += ps[n * 8 + c] * scl;
                ctxv += pctx[(size_t)(n * 8 + c) * 512 + k] * scl;
            }
            attc[(size_t)(t + 1) * 16384 + (size_t)k * 32 + n] = ctxv / Z;
        }
        grid.sync();
    }
}

// ---------------- MLP hidden GEMM: hidden[4128][512] = tanh([h1,attc] @ W1.T + b1) ----------------
__global__ __launch_bounds__(256) void k_mlp(const float* __restrict__ h1a,
                                             const float* __restrict__ attc,
                                             const float* __restrict__ W1,
                                             const float* __restrict__ b1,
                                             float* __restrict__ hidden) {
    __shared__ __align__(16) float At[32 * 33];
    __shared__ __align__(16) float Bt[32 * 68];
    const int t = blockIdx.x, j0 = blockIdx.y * 64, tid = threadIdx.x;
    const int ty = tid >> 4, tx = tid & 15;
    float acc[8];
#pragma unroll
    for (int i = 0; i < 8; ++i) acc[i] = 0.0f;
    for (int k0 = 0; k0 < 1024; k0 += 32) {
        const float* src = (k0 < 512) ? (h1a + (size_t)(t + 1) * 16384 + (size_t)k0 * 32)
                                      : (attc + (size_t)(t + 1) * 16384 + (size_t)(k0 - 512) * 32);
        __syncthreads();
        {
            int kk = tid >> 3, n4 = tid & 7;
            float4 v = *(const float4*)(src + (size_t)kk * 32 + n4 * 4);
            At[kk * 33 + n4 * 4 + 0] = v.x;
            At[kk * 33 + n4 * 4 + 1] = v.y;
            At[kk * 33 + n4 * 4 + 2] = v.z;
            At[kk * 33 + n4 * 4 + 3] = v.w;
#pragma unroll
            for (int i2 = 0; i2 < 2; ++i2) {
                int f = tid + 256 * i2;
                int j = f >> 3, kb = f & 7;
                float4 w = *(const float4*)(W1 + (size_t)(j0 + j) * 1024 + k0 + kb * 4);
                Bt[(kb * 4 + 0) * 68 + j] = w.x;
                Bt[(kb * 4 + 1) * 68 + j] = w.y;
                Bt[(kb * 4 + 2) * 68 + j] = w.z;
                Bt[(kb * 4 + 3) * 68 + j] = w.w;
            }
        }
        __syncthreads();
#pragma unroll
        for (int kk = 0; kk < 32; ++kk) {
            float a0 = At[kk * 33 + ty], a1 = At[kk * 33 + ty + 16];
            float4 b4 = *(const float4*)&Bt[kk * 68 + tx * 4];
            acc[0] += a0 * b4.x; acc[1] += a0 * b4.y; acc[2] += a0 * b4.z; acc[3] += a0 * b4.w;
            acc[4] += a1 * b4.x; acc[5] += a1 * b4.y; acc[6] += a1 * b4.z; acc[7] += a1 * b4.w;
        }
    }
    int j = j0 + tx * 4;
    float4 bv = *(const float4*)(b1 + j);
    int r0 = t * 32;
    float4 o0 = {tanhf(acc[0] + bv.x), tanhf(acc[1] + bv.y), tanhf(acc[2] + bv.z), tanhf(acc[3] + bv.w)};
    float4 o1 = {tanhf(acc[4] + bv.x), tanhf(acc[5] + bv.y), tanhf(acc[6] + bv.z), tanhf(acc[7] + bv.w)};
    *(float4*)(hidden + (size_t)(r0 + ty) * 512 + j) = o0;
    *(float4*)(hidden + (size_t)(r0 + ty + 16) * 512 + j) = o1;
}

// ---------------- fused logits + chunk logsumexp ----------------
// grid (129, 16): block computes 256 vocab rows x 32 samples, chunk-local (max, sumexp) + target logit
__global__ __launch_bounds__(256) void k_ce(const float* __restrict__ hidden,
                                            const float* __restrict__ W2,
                                            const float* __restrict__ b2,
                                            const int* __restrict__ padded,
                                            float* __restrict__ cpm, float* __restrict__ cps,
                                            float* __restrict__ tgt) {
    __shared__ __align__(16) float lg[256 * 33];
    __shared__ float mred[8 * 32];
    __shared__ float Mf[32];
    __shared__ float sred[8 * 32];
    const int t = blockIdx.x, vc = blockIdx.y, tid = threadIdx.x;
    const int v = vc * 256 + tid;
    const float* hrow = hidden + (size_t)t * 32 * 512;
    if (v < V) {
        float acc[32];
#pragma unroll
        for (int n = 0; n < 32; ++n) acc[n] = 0.0f;
        const float* w = W2 + (size_t)v * 512;
        for (int k4 = 0; k4 < 128; ++k4) {
            float4 a = *(const float4*)(w + k4 * 4);
#pragma unroll
            for (int n = 0; n < 32; ++n) {
                float4 h = *(const float4*)(hrow + (size_t)n * 512 + k4 * 4);
                acc[n] += a.x * h.x + a.y * h.y + a.z * h.z + a.w * h.w;
            }
        }
        float bb = b2[v];
#pragma unroll
        for (int n = 0; n < 32; ++n) lg[tid * 33 + n] = acc[n] + bb;
    } else {
#pragma unroll
        for (int n = 0; n < 32; ++n) lg[tid * 33 + n] = -1e30f;
    }
    __syncthreads();
    {
        int n = tid & 31, c = tid >> 5;
        float m = -1e30f;
        for (int i = 0; i < 32; ++i) m = fmaxf(m, lg[(c * 32 + i) * 33 + n]);
        mred[c * 32 + n] = m;
    }
    __syncthreads();
    if (tid < 32) {
        float M = mred[tid];
#pragma unroll
        for (int c = 1; c < 8; ++c) M = fmaxf(M, mred[c * 32 + tid]);
        Mf[tid] = M;
    }
    __syncthreads();
    {
        int n = tid & 31, c = tid >> 5;
        float M = Mf[n], s = 0.0f;
        for (int i = 0; i < 32; ++i) s += __expf(lg[(c * 32 + i) * 33 + n] - M);
        sred[c * 32 + n] = s;
    }
    __syncthreads();
    if (tid < 32) {
        int n = tid;
        float S = 0.0f;
#pragma unroll
        for (int c = 0; c < 8; ++c) S += sred[c * 32 + n];
        int r = t * 32 + n;
        cpm[(size_t)r * 16 + vc] = Mf[n];
        cps[(size_t)r * 16 + vc] = S;
        int vstar = (t < 128) ? padded[n * 128 + t] : 2;
        int vl = vstar - vc * 256;
        if (vl >= 0 && vl < 256) tgt[r] = lg[vl * 33 + n];
    }
}

// ---------------- final combine + CE reduction ----------------
__global__ __launch_bounds__(256) void k_final(const float* __restrict__ cpm,
                                               const float* __restrict__ cps,
                                               const float* __restrict__ tgt,
                                               float* __restrict__ out) {
    __shared__ float red[256];
    float local = 0.0f;
    for (int r = threadIdx.x; r < 4128; r += 256) {
        float M = -1e30f;
#pragma unroll
        for (int c = 0; c < 16; ++c) M = fmaxf(M, cpm[(size_t)r * 16 + c]);
        float S = 0.0f;
#pragma unroll
        for (int c = 0; c < 16; ++c) S += cps[(size_t)r * 16 + c] * __expf(cpm[(size_t)r * 16 + c] - M);
        local += (M + logf(S)) - tgt[r];
    }
    red[threadIdx.x] = local;
    __syncthreads();
    for (int o = 128; o; o >>= 1) {
        if (threadIdx.x < o) red[threadIdx.x] += red[threadIdx.x + o];
        __syncthreads();
    }
    if (threadIdx.x == 0) out[0] = red[0] * (128.0f / 4128.0f);
}

extern "C" void kernel_launch(void* const* d_in, const int* in_sizes, int n_in,
                              void* d_out, int out_size, void* d_ws, size_t ws_size,
                              hipStream_t stream) {
    const int*   padded = (const int*)d_in[0];
    const float* enc    = (const float*)d_in[1];
    const float* emb    = (const float*)d_in[2];
    const float* W_ih0  = (const float*)d_in[3];
    const float* b_ih0  = (const float*)d_in[4];
    const float* W_hh0  = (const float*)d_in[5];
    const float* b_hh0  = (const float*)d_in[6];
    const float* W_ih1  = (const float*)d_in[7];
    const float* b_ih1  = (const float*)d_in[8];
    const float* W_hh1  = (const float*)d_in[9];
    const float* b_hh1  = (const float*)d_in[10];
    const float* W1     = (const float*)d_in[11];
    const float* b1     = (const float*)d_in[12];
    const float* W2     = (const float*)d_in[13];
    const float* b2     = (const float*)d_in[14];
    float* ws  = (float*)d_ws;
    float* out = (float*)d_out;

    hipLaunchKernelGGL(k_init, dim3(320), dim3(256), 0, stream, ws);
    hipLaunchKernelGGL(k_pack0, dim3(8192), dim3(256), 0, stream, W_ih0, W_hh0, ws + OFF_WP0);
    hipLaunchKernelGGL(k_pack1, dim3(8192), dim3(256), 0, stream, W_ih1, W_hh1, ws + OFF_WP1);
    hipLaunchKernelGGL(k_xpre, dim3(129, 32), dim3(256), 0, stream,
                       padded, emb, W_ih0, b_ih0, b_hh0, ws + OFF_XPRE);
    {
        const int* padded_a = padded;
        const float* enc_a = enc;
        const float* bia = b_ih1;
        const float* bib = b_hh1;
        void* args[] = {(void*)&ws, (void*)&padded_a, (void*)&enc_a, (void*)&bia, (void*)&bib};
        hipLaunchCooperativeKernel((void*)k_seq, dim3(256), dim3(256), args, 0, stream);
    }
    hipLaunchKernelGGL(k_mlp, dim3(129, 8), dim3(256), 0, stream,
                       ws + OFF_H1A, ws + OFF_ATTC, W1, b1, ws + OFF_HID);
    hipLaunchKernelGGL(k_ce, dim3(129, 16), dim3(256), 0, stream,
                       ws + OFF_HID, W2, b2, padded, ws + OFF_CPM, ws + OFF_CPS, ws + OFF_TGT);
    hipLaunchKernelGGL(k_final, dim3(1), dim3(256), 0, stream,
                       ws + OFF_CPM, ws + OFF_CPS, ws + OFF_TGT, out);
}

// Round 2
// 9327.717 us; speedup vs baseline: 2.0015x; 2.0015x over previous
//
#include <hip/hip_runtime.h>

// Problem constants
constexpr int V = 4000, E = 512, H = 512, NB = 32, To = 128, Ti = 512;
constexpr int T_STEPS = 129;          // To + 1

// ws layout (float offsets)
constexpr size_t OFF_XPRE = 0;                               // [129][32][2048]
constexpr size_t OFF_WP0  = OFF_XPRE + (size_t)129*32*2048;  // [256][1024][8]
constexpr size_t OFF_WP1  = OFF_WP0 + (size_t)256*1024*8;
constexpr size_t OFF_H0   = OFF_WP1 + (size_t)256*1024*8;    // [2][512][32]
constexpr size_t OFF_C0   = OFF_H0 + 2*512*32;               // [512][32]
constexpr size_t OFF_C1   = OFF_C0 + 512*32;
constexpr size_t OFF_H1A  = OFF_C1 + 512*32;                 // [130][512][32]
constexpr size_t OFF_ATTC = OFF_H1A + (size_t)130*512*32;    // [130][512][32]
constexpr size_t OFF_HID  = OFF_ATTC + (size_t)130*512*32;   // [4128][512]
constexpr size_t OFF_PM   = OFF_HID + (size_t)4128*512;      // [256]
constexpr size_t OFF_PS   = OFF_PM + 256;                    // [256]
constexpr size_t OFF_PCTX = OFF_PS + 256;                    // [256][512]
constexpr size_t OFF_CPM  = OFF_PCTX + (size_t)256*512;      // [4128][16]
constexpr size_t OFF_CPS  = OFF_CPM + (size_t)4128*16;
constexpr size_t OFF_TGT  = OFF_CPS + (size_t)4128*16;       // [4128]
constexpr size_t OFF_BARS = OFF_TGT + 4128;                  // [640] barrier counters

__device__ __forceinline__ float sigmf(float x) { return 1.0f / (1.0f + __expf(-x)); }
__device__ __forceinline__ float bfl(unsigned u) { return __uint_as_float(u << 16); }
__device__ __forceinline__ float bfh(unsigned u) { return __uint_as_float(u & 0xffff0000u); }
__device__ __forceinline__ unsigned short f2b(float x) {
    unsigned u = __float_as_uint(x);
    unsigned r = (u + 0x7fffu + ((u >> 16) & 1u)) >> 16;
    return (unsigned short)r;
}

// Lean grid barrier: one fresh counter per invocation (zeroed by k_init); no reset, no ABA.
__device__ __forceinline__ void gbar(unsigned* bar) {
    __syncthreads();
    if (threadIdx.x == 0) {
        __hip_atomic_fetch_add(bar, 1u, __ATOMIC_ACQ_REL, __HIP_MEMORY_SCOPE_AGENT);
        while (__hip_atomic_load(bar, __ATOMIC_RELAXED, __HIP_MEMORY_SCOPE_AGENT) < 256u)
            __builtin_amdgcn_s_sleep(4);
        (void)__hip_atomic_load(bar, __ATOMIC_ACQUIRE, __HIP_MEMORY_SCOPE_AGENT);
    }
    __syncthreads();
}

// ---------------- init: zero state buffers + barrier counters ----------------
__global__ __launch_bounds__(256) void k_init(float* ws) {
    int id = blockIdx.x * 256 + threadIdx.x;   // 0..82687
    if (id < 81920) {
        int reg = id / 16384, off = id % 16384;
        size_t base;
        switch (reg) {
            case 0: base = OFF_H0; break;          // h0 ping buf 0
            case 1: base = OFF_C0; break;
            case 2: base = OFF_C1; break;
            case 3: base = OFF_H1A; break;         // h1_all slab 0
            default: base = OFF_ATTC; break;       // attc_all slab 0
        }
        ws[base + off] = 0.0f;
    } else if (id < 81920 + 640) {
        ws[OFF_BARS + (id - 81920)] = 0.0f;        // bit-zero == unsigned 0
    }
}

// ---------------- weight pre-pack for the recurrent skinny GEMMs ----------------
// Wp[b][k][r], b=0..255 owns 8 g-rows: gRow = (r>>1)*512 + b*2 + (r&1)
__global__ __launch_bounds__(256) void k_pack0(const float* __restrict__ W_ih0,
                                               const float* __restrict__ W_hh0,
                                               float* __restrict__ Wp) {
    int p = blockIdx.x * 256 + threadIdx.x;    // 0..2097151
    int r = p & 7, k = (p >> 3) & 1023, b = p >> 13;
    int gRow = ((r >> 1) & 3) * 512 + b * 2 + (r & 1);
    float v = (k < 512) ? W_ih0[(size_t)gRow * 1024 + 512 + k]
                        : W_hh0[(size_t)gRow * 512 + (k - 512)];
    Wp[p] = v;
}
__global__ __launch_bounds__(256) void k_pack1(const float* __restrict__ W_ih1,
                                               const float* __restrict__ W_hh1,
                                               float* __restrict__ Wp) {
    int p = blockIdx.x * 256 + threadIdx.x;
    int r = p & 7, k = (p >> 3) & 1023, b = p >> 13;
    int gRow = ((r >> 1) & 3) * 512 + b * 2 + (r & 1);
    float v = (k < 512) ? W_ih1[(size_t)gRow * 512 + k]
                        : W_hh1[(size_t)gRow * 512 + (k - 512)];
    Wp[p] = v;
}

// ---------------- X_pre GEMM: [4128][2048] = emb_rows @ W_ih0[:, :512].T + biases ----------------
__global__ __launch_bounds__(256) void k_xpre(const int* __restrict__ padded,
                                              const float* __restrict__ embedding,
                                              const float* __restrict__ W_ih0,
                                              const float* __restrict__ b_ih0,
                                              const float* __restrict__ b_hh0,
                                              float* __restrict__ Xpre) {
    __shared__ __align__(16) float At[32 * 33];
    __shared__ __align__(16) float Bt[32 * 68];
    __shared__ int toks[32];
    const int t = blockIdx.x, j0 = blockIdx.y * 64, tid = threadIdx.x;
    if (tid < 32) toks[tid] = (t == 0) ? 1 : padded[tid * 128 + (t - 1)];
    __syncthreads();
    const int ty = tid >> 4, tx = tid & 15;
    float acc[8];
#pragma unroll
    for (int i = 0; i < 8; ++i) acc[i] = 0.0f;
    for (int k0 = 0; k0 < 512; k0 += 32) {
        __syncthreads();
        {
            int r = tid >> 3, kk4 = tid & 7;
            float4 v = *(const float4*)(embedding + (size_t)toks[r] * 512 + k0 + kk4 * 4);
            At[(kk4 * 4 + 0) * 33 + r] = v.x;
            At[(kk4 * 4 + 1) * 33 + r] = v.y;
            At[(kk4 * 4 + 2) * 33 + r] = v.z;
            At[(kk4 * 4 + 3) * 33 + r] = v.w;
#pragma unroll
            for (int i2 = 0; i2 < 2; ++i2) {
                int f = tid + 256 * i2;
                int j = f >> 3, kb = f & 7;
                float4 w = *(const float4*)(W_ih0 + (size_t)(j0 + j) * 1024 + k0 + kb * 4);
                Bt[(kb * 4 + 0) * 68 + j] = w.x;
                Bt[(kb * 4 + 1) * 68 + j] = w.y;
                Bt[(kb * 4 + 2) * 68 + j] = w.z;
                Bt[(kb * 4 + 3) * 68 + j] = w.w;
            }
        }
        __syncthreads();
#pragma unroll
        for (int kk = 0; kk < 32; ++kk) {
            float a0 = At[kk * 33 + ty], a1 = At[kk * 33 + ty + 16];
            float4 b4 = *(const float4*)&Bt[kk * 68 + tx * 4];
            acc[0] += a0 * b4.x; acc[1] += a0 * b4.y; acc[2] += a0 * b4.z; acc[3] += a0 * b4.w;
            acc[4] += a1 * b4.x; acc[5] += a1 * b4.y; acc[6] += a1 * b4.z; acc[7] += a1 * b4.w;
        }
    }
    int j = j0 + tx * 4;
    float4 bi = *(const float4*)(b_ih0 + j);
    float4 bh = *(const float4*)(b_hh0 + j);
    int r0 = t * 32;
    float4 o0 = {acc[0] + bi.x + bh.x, acc[1] + bi.y + bh.y, acc[2] + bi.z + bh.z, acc[3] + bi.w + bh.w};
    float4 o1 = {acc[4] + bi.x + bh.x, acc[5] + bi.y + bh.y, acc[6] + bi.z + bh.z, acc[7] + bi.w + bh.w};
    *(float4*)(Xpre + (size_t)(r0 + ty) * 2048 + j) = o0;
    *(float4*)(Xpre + (size_t)(r0 + ty + 16) * 2048 + j) = o1;
}

// ---------------- LSTM phase: weights resident in LDS ----------------
// Block owns 8 g-rows (4 gates x 2 h-cols). Thread (q=tid>>5, kq=tid&31):
// outer-product 8 rows x 4 samples; K staged in 128-row tiles.
__device__ __forceinline__ void lstm_phase(
    const float* __restrict__ lds_wp,    // [1024][8] this pack, in LDS
    const float* __restrict__ srcA,      // K 0..511 source, [k][32] global
    const float* __restrict__ srcB,      // K 512..1023 source, [k][32] global
    const float* __restrict__ xpre_row,  // Xpre + t*32*2048, or nullptr
    const float* __restrict__ bia, const float* __restrict__ bib,
    float* __restrict__ cT, float* __restrict__ hOut,
    int b, int tid, int q, int kq, float* lds_s, float* gv) {
    float acc[8][4];
#pragma unroll
    for (int r = 0; r < 8; ++r)
#pragma unroll
        for (int s = 0; s < 4; ++s) acc[r][s] = 0.0f;

#pragma unroll 2
    for (int tt = 0; tt < 8; ++tt) {
        const float* src = (tt < 4) ? (srcA + tt * 128 * 32) : (srcB + (tt - 4) * 128 * 32);
        __syncthreads();
#pragma unroll
        for (int j = 0; j < 4; ++j) {
            int f = tid + j * 256;              // float4 idx within 128x32 tile
            int lk = f >> 3, n4 = f & 7;
            float4 v = ((const float4*)src)[f];
            *(float4*)(lds_s + lk * 40 + n4 * 4) = v;
        }
        __syncthreads();
#pragma unroll
        for (int i = 0; i < 4; ++i) {
            int lk = kq + 32 * i;
            const float* wp = lds_wp + (size_t)(tt * 128 + lk) * 8;
            float4 wA = *(const float4*)(wp);
            float4 wB = *(const float4*)(wp + 4);
            float4 x4 = *(const float4*)(lds_s + lk * 40 + (q << 2));
            acc[0][0] += wA.x * x4.x; acc[0][1] += wA.x * x4.y; acc[0][2] += wA.x * x4.z; acc[0][3] += wA.x * x4.w;
            acc[1][0] += wA.y * x4.x; acc[1][1] += wA.y * x4.y; acc[1][2] += wA.y * x4.z; acc[1][3] += wA.y * x4.w;
            acc[2][0] += wA.z * x4.x; acc[2][1] += wA.z * x4.y; acc[2][2] += wA.z * x4.z; acc[2][3] += wA.z * x4.w;
            acc[3][0] += wA.w * x4.x; acc[3][1] += wA.w * x4.y; acc[3][2] += wA.w * x4.z; acc[3][3] += wA.w * x4.w;
            acc[4][0] += wB.x * x4.x; acc[4][1] += wB.x * x4.y; acc[4][2] += wB.x * x4.z; acc[4][3] += wB.x * x4.w;
            acc[5][0] += wB.y * x4.x; acc[5][1] += wB.y * x4.y; acc[5][2] += wB.y * x4.z; acc[5][3] += wB.y * x4.w;
            acc[6][0] += wB.z * x4.x; acc[6][1] += wB.z * x4.y; acc[6][2] += wB.z * x4.z; acc[6][3] += wB.z * x4.w;
            acc[7][0] += wB.w * x4.x; acc[7][1] += wB.w * x4.y; acc[7][2] += wB.w * x4.z; acc[7][3] += wB.w * x4.w;
        }
    }
    // cross-kq reduction, 2 chunks of 4 rows: layout [n][r*33+kq] (writes conflict-free)
#pragma unroll
    for (int c = 0; c < 2; ++c) {
        __syncthreads();
#pragma unroll
        for (int r = 0; r < 4; ++r)
#pragma unroll
            for (int s = 0; s < 4; ++s)
                lds_s[(q * 4 + s) * 132 + r * 33 + kq] = acc[c * 4 + r][s];
        __syncthreads();
        if (tid < 128) {
            int rr = tid >> 5, n = tid & 31;
            float g = 0.0f;
#pragma unroll
            for (int k2 = 0; k2 < 32; ++k2) g += lds_s[n * 132 + rr * 33 + k2];
            gv[(c * 4 + rr) * 33 + n] = g;
        }
    }
    __syncthreads();
    if (tid < 64) {
        int jl = tid >> 5, nn = tid & 31;
        float gi = gv[(0 + jl) * 33 + nn];
        float gf = gv[(2 + jl) * 33 + nn];
        float gg = gv[(4 + jl) * 33 + nn];
        float go = gv[(6 + jl) * 33 + nn];
        int j = b * 2 + jl;
        if (xpre_row) {
            const float* xp = xpre_row + (size_t)nn * 2048;
            gi += xp[j]; gf += xp[512 + j]; gg += xp[1024 + j]; go += xp[1536 + j];
        } else {
            gi += bia[j] + bib[j];
            gf += bia[512 + j] + bib[512 + j];
            gg += bia[1024 + j] + bib[1024 + j];
            go += bia[1536 + j] + bib[1536 + j];
        }
        float c = cT[j * 32 + nn];
        float cn = sigmf(gf) * c + sigmf(gi) * tanhf(gg);
        float hn = sigmf(go) * tanhf(cn);
        cT[j * 32 + nn] = cn;
        hOut[j * 32 + nn] = hn;
    }
}

// ---------------- cooperative sequential kernel (custom barrier) ----------------
__global__ __launch_bounds__(256, 1) void k_seq(float* ws,
                                                const float* __restrict__ enc,
                                                const float* __restrict__ b_ih1,
                                                const float* __restrict__ b_hh1) {
    __shared__ __align__(16) float lds_w[16384];            // 64 KB: both weight packs
    __shared__ __align__(16) float lds_s[5120];             // 20 KB: staging / reduction / attn scratch
    __shared__ __align__(16) float gv[264];                 // gate sums
    __shared__ __align__(16) unsigned short lds_e[33280];   // 65 KB: enc slice bf16 [64][520]

    const int b = blockIdx.x, tid = threadIdx.x;
    const int q = tid >> 5, kq = tid & 31;

    float* Xpre = ws + OFF_XPRE;
    float* h0   = ws + OFF_H0;
    float* c0   = ws + OFF_C0;
    float* c1   = ws + OFF_C1;
    float* h1a  = ws + OFF_H1A;
    float* attc = ws + OFF_ATTC;
    float* pm   = ws + OFF_PM;
    float* ps   = ws + OFF_PS;
    float* pctx = ws + OFF_PCTX;
    unsigned* bars = (unsigned*)(ws + OFF_BARS);

    // ---- one-time LDS residency: weight packs (fp32) + enc slice (bf16) ----
    {
        const float4* w0 = (const float4*)(ws + OFF_WP0 + (size_t)b * 8192);
        const float4* w1 = (const float4*)(ws + OFF_WP1 + (size_t)b * 8192);
        for (int f = tid; f < 2048; f += 256) ((float4*)lds_w)[f] = w0[f];
        for (int f = tid; f < 2048; f += 256) ((float4*)(lds_w + 8192))[f] = w1[f];
        const int n = b >> 3, ts0 = (b & 7) * 64;
        const float4* encn = (const float4*)(enc + ((size_t)n * 512 + ts0) * 512);
#pragma unroll 4
        for (int j = 0; j < 32; ++j) {
            int f = tid + j * 256;              // 0..8191 float4 of [64][512]
            int row = f >> 7, c4 = f & 127;
            float4 v = encn[(size_t)row * 128 + c4];
            ushort4 o;
            o.x = f2b(v.x); o.y = f2b(v.y); o.z = f2b(v.z); o.w = f2b(v.w);
            *(ushort4*)(lds_e + (size_t)row * 520 + c4 * 4) = o;
        }
    }
    __syncthreads();

    for (int t = 0; t < T_STEPS; ++t) {
        const int rd0 = t & 1, wr0 = rd0 ^ 1;
        // ---- P1: LSTM0 : x = [attc(t), h0(t-1)] ----
        lstm_phase(lds_w, attc + (size_t)t * 16384, h0 + (size_t)rd0 * 16384,
                   Xpre + (size_t)t * 32 * 2048, nullptr, nullptr,
                   c0, h0 + (size_t)wr0 * 16384, b, tid, q, kq, lds_s, gv);
        gbar(bars + t * 4 + 0);
        // ---- P2: LSTM1 : x = [h0(t), h1(t-1)] ----
        lstm_phase(lds_w + 8192, h0 + (size_t)wr0 * 16384, h1a + (size_t)t * 16384,
                   nullptr, b_ih1, b_hh1,
                   c1, h1a + (size_t)(t + 1) * 16384, b, tid, q, kq, lds_s, gv);
        gbar(bars + t * 4 + 1);
        // ---- P3a: attention partial (8 blocks per sample, 64 frames each, enc in LDS) ----
        {
            const int n = b >> 3;
            float* h_l = lds_s;          // 512
            float* scp = lds_s + 512;    // 256
            float* p_l = lds_s + 768;    // 64
            const float* h1t = h1a + (size_t)(t + 1) * 16384;
            {
                int k0 = tid * 2;
                h_l[k0]     = h1t[(size_t)k0 * 32 + n];
                h_l[k0 + 1] = h1t[(size_t)(k0 + 1) * 32 + n];
            }
            __syncthreads();
            {
                int ti = tid >> 2, kp = tid & 3;
                const unsigned short* er = lds_e + (size_t)ti * 520 + kp * 128;
                const float* hr = h_l + kp * 128;
                float s = 0.0f;
#pragma unroll
                for (int k8 = 0; k8 < 16; ++k8) {
                    uint4 u = *(const uint4*)(er + k8 * 8);
                    const float* h8 = hr + k8 * 8;
                    s += bfl(u.x) * h8[0] + bfh(u.x) * h8[1]
                       + bfl(u.y) * h8[2] + bfh(u.y) * h8[3]
                       + bfl(u.z) * h8[4] + bfh(u.z) * h8[5]
                       + bfl(u.w) * h8[6] + bfh(u.w) * h8[7];
                }
                scp[kp * 64 + ti] = s;
            }
            __syncthreads();
            if (tid < 64) {
                float sc = scp[tid] + scp[64 + tid] + scp[128 + tid] + scp[192 + tid];
                float m = sc;
                for (int o = 32; o; o >>= 1) m = fmaxf(m, __shfl_xor(m, o));
                float e = __expf(sc - m);
                float z = e;
                for (int o = 32; o; o >>= 1) z += __shfl_xor(z, o);
                p_l[tid] = e;
                if (tid == 0) { pm[b] = m; ps[b] = z; }
            }
            __syncthreads();
            {
                int k2 = tid * 2;
                float cv0 = 0.0f, cv1 = 0.0f;
                const unsigned short* eb = lds_e + k2;
#pragma unroll 8
                for (int ti = 0; ti < 64; ++ti) {
                    float w = p_l[ti];
                    unsigned u = *(const unsigned*)(eb + (size_t)ti * 520);
                    cv0 += w * bfl(u); cv1 += w * bfh(u);
                }
                float2 o2 = {cv0, cv1};
                *(float2*)&pctx[(size_t)b * 512 + k2] = o2;
            }
        }
        gbar(bars + t * 4 + 2);
        // ---- P3b: combine softmax partials -> attc(t+1) ----
        if (b < 64) {
            int n = b >> 1, kh = (b & 1) * 256;
            int k = kh + tid;
            float M = -1e30f;
#pragma unroll
            for (int c = 0; c < 8; ++c) M = fmaxf(M, pm[n * 8 + c]);
            float Z = 0.0f, ctxv = 0.0f;
#pragma unroll
            for (int c = 0; c < 8; ++c) {
                float scl = __expf(pm[n * 8 + c] - M);
                Z += ps[n * 8 + c] * scl;
                ctxv += pctx[(size_t)(n * 8 + c) * 512 + k] * scl;
            }
            attc[(size_t)(t + 1) * 16384 + (size_t)k * 32 + n] = ctxv / Z;
        }
        gbar(bars + t * 4 + 3);
    }
}

// ---------------- MLP hidden GEMM: hidden[4128][512] = tanh([h1,attc] @ W1.T + b1) ----------------
__global__ __launch_bounds__(256) void k_mlp(const float* __restrict__ h1a,
                                             const float* __restrict__ attc,
                                             const float* __restrict__ W1,
                                             const float* __restrict__ b1,
                                             float* __restrict__ hidden) {
    __shared__ __align__(16) float At[32 * 33];
    __shared__ __align__(16) float Bt[32 * 68];
    const int t = blockIdx.x, j0 = blockIdx.y * 64, tid = threadIdx.x;
    const int ty = tid >> 4, tx = tid & 15;
    float acc[8];
#pragma unroll
    for (int i = 0; i < 8; ++i) acc[i] = 0.0f;
    for (int k0 = 0; k0 < 1024; k0 += 32) {
        const float* src = (k0 < 512) ? (h1a + (size_t)(t + 1) * 16384 + (size_t)k0 * 32)
                                      : (attc + (size_t)(t + 1) * 16384 + (size_t)(k0 - 512) * 32);
        __syncthreads();
        {
            int kk = tid >> 3, n4 = tid & 7;
            float4 v = *(const float4*)(src + (size_t)kk * 32 + n4 * 4);
            At[kk * 33 + n4 * 4 + 0] = v.x;
            At[kk * 33 + n4 * 4 + 1] = v.y;
            At[kk * 33 + n4 * 4 + 2] = v.z;
            At[kk * 33 + n4 * 4 + 3] = v.w;
#pragma unroll
            for (int i2 = 0; i2 < 2; ++i2) {
                int f = tid + 256 * i2;
                int j = f >> 3, kb = f & 7;
                float4 w = *(const float4*)(W1 + (size_t)(j0 + j) * 1024 + k0 + kb * 4);
                Bt[(kb * 4 + 0) * 68 + j] = w.x;
                Bt[(kb * 4 + 1) * 68 + j] = w.y;
                Bt[(kb * 4 + 2) * 68 + j] = w.z;
                Bt[(kb * 4 + 3) * 68 + j] = w.w;
            }
        }
        __syncthreads();
#pragma unroll
        for (int kk = 0; kk < 32; ++kk) {
            float a0 = At[kk * 33 + ty], a1 = At[kk * 33 + ty + 16];
            float4 b4 = *(const float4*)&Bt[kk * 68 + tx * 4];
            acc[0] += a0 * b4.x; acc[1] += a0 * b4.y; acc[2] += a0 * b4.z; acc[3] += a0 * b4.w;
            acc[4] += a1 * b4.x; acc[5] += a1 * b4.y; acc[6] += a1 * b4.z; acc[7] += a1 * b4.w;
        }
    }
    int j = j0 + tx * 4;
    float4 bv = *(const float4*)(b1 + j);
    int r0 = t * 32;
    float4 o0 = {tanhf(acc[0] + bv.x), tanhf(acc[1] + bv.y), tanhf(acc[2] + bv.z), tanhf(acc[3] + bv.w)};
    float4 o1 = {tanhf(acc[4] + bv.x), tanhf(acc[5] + bv.y), tanhf(acc[6] + bv.z), tanhf(acc[7] + bv.w)};
    *(float4*)(hidden + (size_t)(r0 + ty) * 512 + j) = o0;
    *(float4*)(hidden + (size_t)(r0 + ty + 16) * 512 + j) = o1;
}

// ---------------- fused logits + chunk logsumexp ----------------
__global__ __launch_bounds__(256) void k_ce(const float* __restrict__ hidden,
                                            const float* __restrict__ W2,
                                            const float* __restrict__ b2,
                                            const int* __restrict__ padded,
                                            float* __restrict__ cpm, float* __restrict__ cps,
                                            float* __restrict__ tgt) {
    __shared__ __align__(16) float lg[256 * 33];
    __shared__ float mred[8 * 32];
    __shared__ float Mf[32];
    __shared__ float sred[8 * 32];
    const int t = blockIdx.x, vc = blockIdx.y, tid = threadIdx.x;
    const int v = vc * 256 + tid;
    const float* hrow = hidden + (size_t)t * 32 * 512;
    if (v < V) {
        float acc[32];
#pragma unroll
        for (int n = 0; n < 32; ++n) acc[n] = 0.0f;
        const float* w = W2 + (size_t)v * 512;
        for (int k4 = 0; k4 < 128; ++k4) {
            float4 a = *(const float4*)(w + k4 * 4);
#pragma unroll
            for (int n = 0; n < 32; ++n) {
                float4 h = *(const float4*)(hrow + (size_t)n * 512 + k4 * 4);
                acc[n] += a.x * h.x + a.y * h.y + a.z * h.z + a.w * h.w;
            }
        }
        float bb = b2[v];
#pragma unroll
        for (int n = 0; n < 32; ++n) lg[tid * 33 + n] = acc[n] + bb;
    } else {
#pragma unroll
        for (int n = 0; n < 32; ++n) lg[tid * 33 + n] = -1e30f;
    }
    __syncthreads();
    {
        int n = tid & 31, c = tid >> 5;
        float m = -1e30f;
        for (int i = 0; i < 32; ++i) m = fmaxf(m, lg[(c * 32 + i) * 33 + n]);
        mred[c * 32 + n] = m;
    }
    __syncthreads();
    if (tid < 32) {
        float M = mred[tid];
#pragma unroll
        for (int c = 1; c < 8; ++c) M = fmaxf(M, mred[c * 32 + tid]);
        Mf[tid] = M;
    }
    __syncthreads();
    {
        int n = tid & 31, c = tid >> 5;
        float M = Mf[n], s = 0.0f;
        for (int i = 0; i < 32; ++i) s += __expf(lg[(c * 32 + i) * 33 + n] - M);
        sred[c * 32 + n] = s;
    }
    __syncthreads();
    if (tid < 32) {
        int n = tid;
        float S = 0.0f;
#pragma unroll
        for (int c = 0; c < 8; ++c) S += sred[c * 32 + n];
        int r = t * 32 + n;
        cpm[(size_t)r * 16 + vc] = Mf[n];
        cps[(size_t)r * 16 + vc] = S;
        int vstar = (t < 128) ? padded[n * 128 + t] : 2;
        int vl = vstar - vc * 256;
        if (vl >= 0 && vl < 256) tgt[r] = lg[vl * 33 + n];
    }
}

// ---------------- final combine + CE reduction ----------------
__global__ __launch_bounds__(256) void k_final(const float* __restrict__ cpm,
                                               const float* __restrict__ cps,
                                               const float* __restrict__ tgt,
                                               float* __restrict__ out) {
    __shared__ float red[256];
    float local = 0.0f;
    for (int r = threadIdx.x; r < 4128; r += 256) {
        float M = -1e30f;
#pragma unroll
        for (int c = 0; c < 16; ++c) M = fmaxf(M, cpm[(size_t)r * 16 + c]);
        float S = 0.0f;
#pragma unroll
        for (int c = 0; c < 16; ++c) S += cps[(size_t)r * 16 + c] * __expf(cpm[(size_t)r * 16 + c] - M);
        local += (M + logf(S)) - tgt[r];
    }
    red[threadIdx.x] = local;
    __syncthreads();
    for (int o = 128; o; o >>= 1) {
        if (threadIdx.x < o) red[threadIdx.x] += red[threadIdx.x + o];
        __syncthreads();
    }
    if (threadIdx.x == 0) out[0] = red[0] * (128.0f / 4128.0f);
}

extern "C" void kernel_launch(void* const* d_in, const int* in_sizes, int n_in,
                              void* d_out, int out_size, void* d_ws, size_t ws_size,
                              hipStream_t stream) {
    const int*   padded = (const int*)d_in[0];
    const float* enc    = (const float*)d_in[1];
    const float* emb    = (const float*)d_in[2];
    const float* W_ih0  = (const float*)d_in[3];
    const float* b_ih0  = (const float*)d_in[4];
    const float* W_hh0  = (const float*)d_in[5];
    const float* b_hh0  = (const float*)d_in[6];
    const float* W_ih1  = (const float*)d_in[7];
    const float* b_ih1  = (const float*)d_in[8];
    const float* W_hh1  = (const float*)d_in[9];
    const float* b_hh1  = (const float*)d_in[10];
    const float* W1     = (const float*)d_in[11];
    const float* b1     = (const float*)d_in[12];
    const float* W2     = (const float*)d_in[13];
    const float* b2     = (const float*)d_in[14];
    float* ws  = (float*)d_ws;
    float* out = (float*)d_out;

    hipLaunchKernelGGL(k_init, dim3(323), dim3(256), 0, stream, ws);
    hipLaunchKernelGGL(k_pack0, dim3(8192), dim3(256), 0, stream, W_ih0, W_hh0, ws + OFF_WP0);
    hipLaunchKernelGGL(k_pack1, dim3(8192), dim3(256), 0, stream, W_ih1, W_hh1, ws + OFF_WP1);
    hipLaunchKernelGGL(k_xpre, dim3(129, 32), dim3(256), 0, stream,
                       padded, emb, W_ih0, b_ih0, b_hh0, ws + OFF_XPRE);
    {
        float* ws_a = ws;
        const float* enc_a = enc;
        const float* bia = b_ih1;
        const float* bib = b_hh1;
        void* args[] = {(void*)&ws_a, (void*)&enc_a, (void*)&bia, (void*)&bib};
        hipLaunchCooperativeKernel((void*)k_seq, dim3(256), dim3(256), args, 0, stream);
    }
    hipLaunchKernelGGL(k_mlp, dim3(129, 8), dim3(256), 0, stream,
                       ws + OFF_H1A, ws + OFF_ATTC, W1, b1, ws + OFF_HID);
    hipLaunchKernelGGL(k_ce, dim3(129, 16), dim3(256), 0, stream,
                       ws + OFF_HID, W2, b2, padded, ws + OFF_CPM, ws + OFF_CPS, ws + OFF_TGT);
    hipLaunchKernelGGL(k_final, dim3(1), dim3(256), 0, stream,
                       ws + OFF_CPM, ws + OFF_CPS, ws + OFF_TGT, out);
}